// Round 18
// baseline (1318.804 us; speedup 1.0000x reference)
//
#include <hip/hip_runtime.h>
#include <hip/hip_cooperative_groups.h>

namespace cg = cooperative_groups;

using u16 = unsigned short;
using u32 = unsigned int;

#define M_NODES 50000
#define E_EDGES 600000
#define EPS_BN 1e-5f
#define BKT 48
#define NBM 512
#define THM (NBM * 256)

typedef __attribute__((ext_vector_type(8))) short bf16x8;
typedef __attribute__((ext_vector_type(4))) float f32x4;

__device__ __forceinline__ float bf2f(u16 v) {
  union { u32 u; float f; } x; x.u = ((u32)v) << 16; return x.f;
}
__device__ __forceinline__ float lo16f(u32 v) {
  union { u32 u; float f; } x; x.u = v << 16; return x.f;
}
__device__ __forceinline__ float hi16f(u32 v) {
  union { u32 u; float f; } x; x.u = v & 0xffff0000u; return x.f;
}
__device__ __forceinline__ u16 f2bf(float f) {
  union { float f; u32 u; } x; x.f = f;
  u32 r = x.u + 0x7fffu + ((x.u >> 16) & 1u);
  return (u16)(r >> 16);
}

// ============================================================================
// ======================  FALLBACK PIPELINE (R17, proven)  ===================
// ============================================================================

__global__ void k_place(const int* __restrict__ src, const int* __restrict__ dst,
                        int* __restrict__ cnt, int* __restrict__ bucket, int n) {
  int e = blockIdx.x * blockDim.x + threadIdx.x;
  if (e < n) {
    int d = dst[e];
    int p = atomicAdd(&cnt[d], 1);
    if (p < BKT) bucket[d * BKT + p] = src[e];
  }
}

__global__ __launch_bounds__(256) void k_prep(const float* __restrict__ encW2,
                                              const float* __restrict__ Wl,
                                              const float* __restrict__ Wr,
                                              const float* __restrict__ decW1,
                                              u16* __restrict__ Bp,
                                              int* __restrict__ cnt0,
                                              float* __restrict__ ssums0) {
  int e = blockIdx.x * 256 + threadIdx.x;
  if (e < M_NODES) cnt0[e] = 0;
  if (e < 1024) ssums0[e] = 0.f;
  float v;
  if (e < 32768) {
    v = encW2[e];
  } else if (e < 196608) {
    int r = e - 32768;
    int i = r >> 15;
    int rr = r & 32767;
    int n = rr >> 8;
    int k = rr & 255;
    v = (k < 128) ? Wl[i * 16384 + n * 128 + k] : Wr[i * 16384 + n * 128 + (k - 128)];
  } else {
    v = decW1[e - 196608];
  }
  Bp[e] = f2bf(v);
}

template <int TRANS>
__global__ __launch_bounds__(256) void k_agg(const u16* __restrict__ z,
                                             const int* __restrict__ cnt,
                                             const int* __restrict__ bucket,
                                             const float* __restrict__ ssum,
                                             const float* __restrict__ gamma,
                                             const float* __restrict__ beta,
                                             u16* __restrict__ mean, int M) {
  __shared__ float s_sc[256];
  int t = threadIdx.x;
  if (TRANS) {
    if (t < 128) {
      float m = ssum[t] * (1.0f / M_NODES);
      float var = ssum[128 + t] * (1.0f / M_NODES) - m * m;
      float s = gamma[t] * rsqrtf(var + EPS_BN);
      s_sc[t] = s;
      s_sc[128 + t] = beta[t] - m * s;
    }
    __syncthreads();
  }
  int lane = t & 63;
  int slot = lane >> 4;
  int fc = lane & 15;
  float sreg[8], treg[8];
  if (TRANS) {
    #pragma unroll
    for (int i = 0; i < 8; ++i) { sreg[i] = s_sc[fc * 8 + i]; treg[i] = s_sc[128 + fc * 8 + i]; }
  }
  int rx = blockIdx.x & 7;
  int kx = blockIdx.x >> 3;
  int strip = rx + 8 * (kx >> 5);
  int nb = strip * 32 + (kx & 31);
  int node = nb * 4 + (t >> 6);
  if (node >= M) return;

  int deg = cnt[node];
  int nd = deg < BKT ? deg : BKT;
  const int* bk = bucket + (size_t)node * BKT;
  float a[8] = {};
  for (int j = slot; j < nd; j += 4) {
    int s = bk[j];
    uint4 v = *(const uint4*)(z + (size_t)s * 128 + fc * 8);
    float f[8] = {lo16f(v.x), hi16f(v.x), lo16f(v.y), hi16f(v.y),
                  lo16f(v.z), hi16f(v.z), lo16f(v.w), hi16f(v.w)};
    #pragma unroll
    for (int i = 0; i < 8; ++i) {
      float vv = TRANS ? fmaxf(fmaf(f[i], sreg[i], treg[i]), 0.f) : f[i];
      a[i] += vv;
    }
  }
  #pragma unroll
  for (int i = 0; i < 8; ++i) {
    a[i] += __shfl_xor(a[i], 16, 64);
    a[i] += __shfl_xor(a[i], 32, 64);
  }
  if (slot == 0) {
    float inv = 1.0f / (float)(deg > 1 ? deg : 1);
    uint4 r;
    r.x = (u32)f2bf(a[0] * inv) | ((u32)f2bf(a[1] * inv) << 16);
    r.y = (u32)f2bf(a[2] * inv) | ((u32)f2bf(a[3] * inv) << 16);
    r.z = (u32)f2bf(a[4] * inv) | ((u32)f2bf(a[5] * inv) << 16);
    r.w = (u32)f2bf(a[6] * inv) | ((u32)f2bf(a[7] * inv) << 16);
    *(uint4*)(mean + (size_t)node * 128 + fc * 8) = r;
  }
}

template <int TRANS, int DO_STATS>
__global__ __launch_bounds__(256) void k_gemm_reg(
    const u16* __restrict__ A1, const u16* __restrict__ A2,
    const u16* __restrict__ Bp, const float* __restrict__ bias,
    u16* __restrict__ C, int M, float* __restrict__ ssum_out,
    const float* __restrict__ ssum_in, const float* __restrict__ gamma,
    const float* __restrict__ beta) {
  __shared__ __align__(16) u16 Bs[8][2048];
  __shared__ float bnbuf[128];
  __shared__ float s_scS[256];
  int t = threadIdx.x;
  int lane = t & 63;
  int w = t >> 6;
  int rx = blockIdx.x & 7;
  int hx = (blockIdx.x >> 3) & 1;
  int qx = blockIdx.x >> 4;
  int s128 = qx * 8 + rx;
  int m0 = s128 * 128;
  if (m0 >= M) return;
  int n0 = hx * 64;
  int fc = lane & 15;
  int c16 = lane >> 4;

  if (DO_STATS && t < 128) bnbuf[t] = 0.f;

  uint4 bst[8];
  #pragma unroll
  for (int j = 0; j < 8; ++j) {
    int s = j * 256 + t;
    int p = s >> 8;
    int sp = s & 255;
    int row = sp >> 2;
    int cc = (sp & 3) ^ ((row >> 1) & 3);
    bst[j] = *(const uint4*)(Bp + (size_t)(n0 + row) * 256 + p * 32 + cc * 8);
  }

  bf16x8 af[8][2];
  int wrb = m0 + w * 32;
  #pragma unroll
  for (int mf = 0; mf < 2; ++mf) {
    int rg = wrb + mf * 16 + fc;
    rg = rg < M ? rg : M - 1;
    const u16* a1r = A1 + (size_t)rg * 128 + c16 * 8;
    const u16* a2r = A2 + (size_t)rg * 128 + c16 * 8;
    #pragma unroll
    for (int kt = 0; kt < 4; ++kt) af[kt][mf] = *(const bf16x8*)(a1r + kt * 32);
    #pragma unroll
    for (int kt = 0; kt < 4; ++kt) af[4 + kt][mf] = *(const bf16x8*)(a2r + kt * 32);
  }

  if (TRANS && t < 128) {
    float m = ssum_in[t] * (1.0f / M_NODES);
    float var = ssum_in[128 + t] * (1.0f / M_NODES) - m * m;
    float s = gamma[t] * rsqrtf(var + EPS_BN);
    s_scS[t] = s;
    s_scS[128 + t] = beta[t] - m * s;
  }

  #pragma unroll
  for (int j = 0; j < 8; ++j) {
    int s = j * 256 + t;
    *(uint4*)&((u16*)Bs)[s * 8] = bst[j];
  }
  __syncthreads();

  if (TRANS) {
    #pragma unroll
    for (int kt = 0; kt < 4; ++kt) {
      #pragma unroll
      for (int mf = 0; mf < 2; ++mf) {
        bf16x8 v = af[4 + kt][mf];
        bf16x8 o;
        #pragma unroll
        for (int i = 0; i < 8; ++i) {
          int feat = kt * 32 + c16 * 8 + i;
          float fv = bf2f((u16)v[i]);
          o[i] = (short)f2bf(fmaxf(fmaf(fv, s_scS[feat], s_scS[128 + feat]), 0.f));
        }
        af[4 + kt][mf] = o;
      }
    }
  }

  f32x4 acc[2][4] = {};
  #pragma unroll
  for (int kt = 0; kt < 8; ++kt) {
    bf16x8 bfr[4];
    #pragma unroll
    for (int nf = 0; nf < 4; ++nf) {
      int row = nf * 16 + fc;
      int cs = c16 ^ ((row >> 1) & 3);
      bfr[nf] = *(const bf16x8*)&Bs[kt][row * 32 + cs * 8];
    }
    #pragma unroll
    for (int mf = 0; mf < 2; ++mf)
      #pragma unroll
      for (int nf = 0; nf < 4; ++nf)
        acc[mf][nf] = __builtin_amdgcn_mfma_f32_16x16x32_bf16(af[kt][mf], bfr[nf], acc[mf][nf], 0, 0, 0);
  }

  float breg[4];
  #pragma unroll
  for (int nf = 0; nf < 4; ++nf) breg[nf] = bias[n0 + nf * 16 + fc];

  __syncthreads();
  u16* Cl = (u16*)Bs;
  float cs_[4] = {}, cq_[4] = {};
  #pragma unroll
  for (int mf = 0; mf < 2; ++mf) {
    #pragma unroll
    for (int j = 0; j < 4; ++j) {
      int rl = w * 32 + mf * 16 + c16 * 4 + j;
      bool valid = (m0 + rl) < M;
      #pragma unroll
      for (int nf = 0; nf < 4; ++nf) {
        float v = acc[mf][nf][j] + breg[nf];
        Cl[rl * 64 + nf * 16 + fc] = f2bf(v);
        if (DO_STATS && valid) { cs_[nf] += v; cq_[nf] = fmaf(v, v, cq_[nf]); }
      }
    }
  }
  __syncthreads();
  #pragma unroll
  for (int j2 = 0; j2 < 4; ++j2) {
    int ci = j2 * 256 + t;
    int row = ci >> 3;
    int cx = ci & 7;
    int rg = m0 + row;
    if (rg < M)
      *(uint4*)(C + (size_t)rg * 128 + n0 + cx * 8) = *(const uint4*)&Cl[row * 64 + cx * 8];
  }

  if (DO_STATS) {
    #pragma unroll
    for (int nf = 0; nf < 4; ++nf) {
      float s = cs_[nf], q = cq_[nf];
      s += __shfl_xor(s, 16, 64); s += __shfl_xor(s, 32, 64);
      q += __shfl_xor(q, 16, 64); q += __shfl_xor(q, 32, 64);
      if (c16 == 0) {
        atomicAdd(&bnbuf[nf * 16 + fc], s);
        atomicAdd(&bnbuf[64 + nf * 16 + fc], q);
      }
    }
    __syncthreads();
    if (t < 128) {
      int idx = (t < 64) ? (n0 + t) : (128 + n0 + (t - 64));
      atomicAdd(&ssum_out[idx], bnbuf[t]);
    }
  }
}

__global__ __launch_bounds__(256) void k_enc(
    const float* __restrict__ x, const float* __restrict__ W1,
    const float* __restrict__ b1, const u16* __restrict__ Bp,
    const float* __restrict__ bias, u16* __restrict__ C, int M) {
  __shared__ __align__(16) u16 As[8][2048];
  __shared__ __align__(16) u16 Bs[8][2048];
  __shared__ float xs[448];
  int t = threadIdx.x;
  int lane = t & 63;
  int w = t >> 6;
  int rx = blockIdx.x & 7;
  int kx = (blockIdx.x >> 3) & 3;
  int qx = blockIdx.x >> 5;
  int s128 = qx * 8 + rx;
  int e64 = s128 * 2 + (kx & 1);
  int m0 = e64 * 64;
  if (m0 >= M) return;
  int n0c = (kx >> 1) * 64;
  int fc = lane & 15;
  int c16 = lane >> 4;

  uint4 bst[8];
  #pragma unroll
  for (int j = 0; j < 8; ++j) {
    int s = j * 256 + t;
    int p = s >> 8;
    int sp = s & 255;
    int row = sp >> 2;
    int cc = (sp & 3) ^ ((row >> 1) & 3);
    bst[j] = *(const uint4*)(Bp + (size_t)(n0c + row) * 256 + p * 32 + cc * 8);
  }
  for (int i = t; i < 448; i += 256) {
    int gi = m0 * 7 + i;
    xs[i] = (gi < M * 7) ? x[gi] : 0.f;
  }
  float w1r[7];
  #pragma unroll
  for (int k = 0; k < 7; ++k) w1r[k] = W1[t * 7 + k];
  float b1r = b1[t];
  __syncthreads();

  int p = t >> 5;
  int cq = (t & 31) >> 3;
  int e8 = t & 7;
  for (int r = 0; r < 64; ++r) {
    float acc = b1r;
    #pragma unroll
    for (int k = 0; k < 7; ++k) acc = fmaf(w1r[k], xs[r * 7 + k], acc);
    As[p][r * 32 + (cq ^ ((r >> 1) & 3)) * 8 + e8] = f2bf(fmaxf(acc, 0.f));
  }
  #pragma unroll
  for (int j = 0; j < 8; ++j) {
    int s = j * 256 + t;
    *(uint4*)&((u16*)Bs)[s * 8] = bst[j];
  }
  __syncthreads();

  f32x4 acc[2][2] = {};
  #pragma unroll
  for (int kt = 0; kt < 8; ++kt) {
    bf16x8 afr[2], bfr[2];
    #pragma unroll
    for (int mf = 0; mf < 2; ++mf) {
      int row = (w & 1) * 32 + mf * 16 + fc;
      int cs = c16 ^ ((row >> 1) & 3);
      afr[mf] = *(const bf16x8*)&As[kt][row * 32 + cs * 8];
    }
    #pragma unroll
    for (int nf = 0; nf < 2; ++nf) {
      int row = (w >> 1) * 32 + nf * 16 + fc;
      int cs = c16 ^ ((row >> 1) & 3);
      bfr[nf] = *(const bf16x8*)&Bs[kt][row * 32 + cs * 8];
    }
    #pragma unroll
    for (int mf = 0; mf < 2; ++mf)
      #pragma unroll
      for (int nf = 0; nf < 2; ++nf)
        acc[mf][nf] = __builtin_amdgcn_mfma_f32_16x16x32_bf16(afr[mf], bfr[nf], acc[mf][nf], 0, 0, 0);
  }

  float breg[2];
  #pragma unroll
  for (int nf = 0; nf < 2; ++nf) breg[nf] = bias[n0c + (w >> 1) * 32 + nf * 16 + fc];
  __syncthreads();
  u16* Cl = (u16*)As;
  #pragma unroll
  for (int mf = 0; mf < 2; ++mf)
    #pragma unroll
    for (int j = 0; j < 4; ++j) {
      int rl = (w & 1) * 32 + mf * 16 + c16 * 4 + j;
      #pragma unroll
      for (int nf = 0; nf < 2; ++nf)
        Cl[rl * 64 + (w >> 1) * 32 + nf * 16 + fc] = f2bf(acc[mf][nf][j] + breg[nf]);
    }
  __syncthreads();
  #pragma unroll
  for (int j2 = 0; j2 < 2; ++j2) {
    int ci = j2 * 256 + t;
    int row = ci >> 3;
    int cx = ci & 7;
    int rg = m0 + row;
    if (rg < M)
      *(uint4*)(C + (size_t)rg * 128 + n0c + cx * 8) = *(const uint4*)&Cl[row * 64 + cx * 8];
  }
}

__global__ __launch_bounds__(256) void k_dec(
    const u16* __restrict__ z5, const u16* __restrict__ Bpd,
    const float* __restrict__ b1, const float* __restrict__ W2,
    const float* __restrict__ b2, float* __restrict__ out, int M) {
  __shared__ __align__(16) u16 Bs[4][8192];
  int t = threadIdx.x;
  int lane = t & 63;
  int w = t >> 6;
  int rx = blockIdx.x & 7;
  int kx = (blockIdx.x >> 3) & 1;
  int qx = blockIdx.x >> 4;
  int s128 = qx * 8 + rx;
  int e64 = s128 * 2 + kx;
  int m0 = e64 * 64;
  if (m0 >= M) return;
  int fc = lane & 15;
  int c16 = lane >> 4;

  bf16x8 af[4];
  {
    int rg = m0 + w * 16 + fc;
    rg = rg < M ? rg : M - 1;
    const u16* ar = z5 + (size_t)rg * 128 + c16 * 8;
    #pragma unroll
    for (int kt = 0; kt < 4; ++kt) af[kt] = *(const bf16x8*)(ar + kt * 32);
  }

  #pragma unroll
  for (int r = 0; r < 2; ++r) {
    uint4 bst[8];
    #pragma unroll
    for (int j = 0; j < 8; ++j) {
      int s = r * 2048 + j * 256 + t;
      int p = s >> 10;
      int sp = s & 1023;
      int row = sp >> 2;
      int cc = (sp & 3) ^ ((row >> 1) & 3);
      bst[j] = *(const uint4*)(Bpd + (size_t)row * 128 + p * 32 + cc * 8);
    }
    #pragma unroll
    for (int j = 0; j < 8; ++j) {
      int s = r * 2048 + j * 256 + t;
      *(uint4*)&((u16*)Bs)[s * 8] = bst[j];
    }
  }
  __syncthreads();

  f32x4 acc[16];
  #pragma unroll
  for (int nf = 0; nf < 16; ++nf) acc[nf] = (f32x4){0.f, 0.f, 0.f, 0.f};
  #pragma unroll
  for (int kt = 0; kt < 4; ++kt) {
    #pragma unroll
    for (int nf = 0; nf < 16; ++nf) {
      int row = nf * 16 + fc;
      int cs = c16 ^ ((row >> 1) & 3);
      bf16x8 bfr = *(const bf16x8*)&Bs[kt][row * 32 + cs * 8];
      acc[nf] = __builtin_amdgcn_mfma_f32_16x16x32_bf16(af[kt], bfr, acc[nf], 0, 0, 0);
    }
  }

  float po[4][4] = {};
  #pragma unroll
  for (int nf = 0; nf < 16; ++nf) {
    int col = nf * 16 + fc;
    float b1v = b1[col];
    float w2v[4];
    #pragma unroll
    for (int o = 0; o < 4; ++o) w2v[o] = W2[o * 256 + col];
    #pragma unroll
    for (int j = 0; j < 4; ++j) {
      float hv = fmaxf(acc[nf][j] + b1v, 0.f);
      #pragma unroll
      for (int o = 0; o < 4; ++o) po[j][o] = fmaf(hv, w2v[o], po[j][o]);
    }
  }
  #pragma unroll
  for (int j = 0; j < 4; ++j)
    #pragma unroll
    for (int o = 0; o < 4; ++o) {
      float v = po[j][o];
      v += __shfl_xor(v, 1, 16);
      v += __shfl_xor(v, 2, 16);
      v += __shfl_xor(v, 4, 16);
      po[j][o] = v + __shfl_xor(v, 8, 16);
    }
  if (fc == 0) {
    #pragma unroll
    for (int j = 0; j < 4; ++j) {
      int rg = m0 + w * 16 + c16 * 4 + j;
      if (rg < M) {
        #pragma unroll
        for (int o = 0; o < 4; ++o) out[(size_t)rg * 4 + o] = po[j][o] + b2[o];
      }
    }
  }
}

// ============================================================================
// ==========================  COOPERATIVE MEGA-KERNEL  =======================
// ============================================================================

struct MP {
  const float* x; const int* src; const int* dst;
  const float* encW1; const float* encb1; const float* encb2;
  const float* encW2; const float* Wl; const float* bl; const float* Wr;
  const float* gamma; const float* beta;
  const float* decW1; const float* decb1; const float* decW2; const float* decb2;
  u16* h; u16* zA; u16* zB; u16* mean; u16* Bpack;
  int* cnt; int* bucket; float* ssums; float* out;
};

__device__ __forceinline__ void mg_gemm(
    const u16* __restrict__ A1, const u16* __restrict__ A2, int strideA,
    const u16* __restrict__ Bp, const float* __restrict__ bias,
    u16* __restrict__ C, float* __restrict__ ssum_out, bool do_stats, bool trans,
    const float* __restrict__ ssum_in, const float* __restrict__ gamma,
    const float* __restrict__ beta, u16* smem, float* aux, int t, int bid) {
  int lane = t & 63;
  int w = t >> 6;
  int fc = lane & 15;
  int c16 = lane >> 4;
  float* s_scS = aux;          // 256
  float* bnbuf = aux + 256;    // 128
  for (int vb = bid; vb < 784; vb += NBM) {
    int rx = vb & 7;
    int hx = (vb >> 3) & 1;
    int qx = vb >> 4;
    int s128 = qx * 8 + rx;
    int m0 = s128 * 128;
    if (m0 >= M_NODES) continue;
    int n0 = hx * 64;

    if (do_stats && t < 128) bnbuf[t] = 0.f;

    uint4 bst[8];
    #pragma unroll
    for (int j = 0; j < 8; ++j) {
      int s = j * 256 + t;
      int p = s >> 8;
      int sp = s & 255;
      int row = sp >> 2;
      int cc = (sp & 3) ^ ((row >> 1) & 3);
      bst[j] = *(const uint4*)(Bp + (size_t)(n0 + row) * 256 + p * 32 + cc * 8);
    }
    bf16x8 af[8][2];
    int wrb = m0 + w * 32;
    #pragma unroll
    for (int mf = 0; mf < 2; ++mf) {
      int rg = wrb + mf * 16 + fc;
      rg = rg < M_NODES ? rg : M_NODES - 1;
      const u16* a1r = A1 + (size_t)rg * strideA + c16 * 8;
      const u16* a2r = A2 + (size_t)rg * strideA + c16 * 8;
      #pragma unroll
      for (int kt = 0; kt < 4; ++kt) af[kt][mf] = *(const bf16x8*)(a1r + kt * 32);
      #pragma unroll
      for (int kt = 0; kt < 4; ++kt) af[4 + kt][mf] = *(const bf16x8*)(a2r + kt * 32);
    }
    if (trans && t < 128) {
      float m = ssum_in[t] * (1.0f / M_NODES);
      float var = ssum_in[128 + t] * (1.0f / M_NODES) - m * m;
      float s = gamma[t] * rsqrtf(var + EPS_BN);
      s_scS[t] = s;
      s_scS[128 + t] = beta[t] - m * s;
    }
    #pragma unroll
    for (int j = 0; j < 8; ++j) {
      int s = j * 256 + t;
      *(uint4*)&smem[s * 8] = bst[j];
    }
    __syncthreads();

    if (trans) {
      #pragma unroll
      for (int kt = 0; kt < 4; ++kt) {
        #pragma unroll
        for (int mf = 0; mf < 2; ++mf) {
          bf16x8 v = af[4 + kt][mf];
          bf16x8 o;
          #pragma unroll
          for (int i = 0; i < 8; ++i) {
            int feat = kt * 32 + c16 * 8 + i;
            float fv = bf2f((u16)v[i]);
            o[i] = (short)f2bf(fmaxf(fmaf(fv, s_scS[feat], s_scS[128 + feat]), 0.f));
          }
          af[4 + kt][mf] = o;
        }
      }
    }

    f32x4 acc[2][4] = {};
    #pragma unroll
    for (int kt = 0; kt < 8; ++kt) {
      bf16x8 bfr[4];
      #pragma unroll
      for (int nf = 0; nf < 4; ++nf) {
        int row = nf * 16 + fc;
        int cs = c16 ^ ((row >> 1) & 3);
        bfr[nf] = *(const bf16x8*)&smem[kt * 2048 * 8 / 8 + row * 32 + cs * 8];
      }
      #pragma unroll
      for (int mf = 0; mf < 2; ++mf)
        #pragma unroll
        for (int nf = 0; nf < 4; ++nf)
          acc[mf][nf] = __builtin_amdgcn_mfma_f32_16x16x32_bf16(af[kt][mf], bfr[nf], acc[mf][nf], 0, 0, 0);
    }

    float breg[4];
    #pragma unroll
    for (int nf = 0; nf < 4; ++nf) breg[nf] = bias[n0 + nf * 16 + fc];

    __syncthreads();
    u16* Cl = smem;
    float cs_[4] = {}, cq_[4] = {};
    #pragma unroll
    for (int mf = 0; mf < 2; ++mf) {
      #pragma unroll
      for (int j = 0; j < 4; ++j) {
        int rl = w * 32 + mf * 16 + c16 * 4 + j;
        bool valid = (m0 + rl) < M_NODES;
        #pragma unroll
        for (int nf = 0; nf < 4; ++nf) {
          float v = acc[mf][nf][j] + breg[nf];
          Cl[rl * 64 + nf * 16 + fc] = f2bf(v);
          if (do_stats && valid) { cs_[nf] += v; cq_[nf] = fmaf(v, v, cq_[nf]); }
        }
      }
    }
    __syncthreads();
    #pragma unroll
    for (int j2 = 0; j2 < 4; ++j2) {
      int ci = j2 * 256 + t;
      int row = ci >> 3;
      int cx = ci & 7;
      int rg = m0 + row;
      if (rg < M_NODES)
        *(uint4*)(C + (size_t)rg * 128 + n0 + cx * 8) = *(const uint4*)&Cl[row * 64 + cx * 8];
    }
    if (do_stats) {
      #pragma unroll
      for (int nf = 0; nf < 4; ++nf) {
        float s = cs_[nf], q = cq_[nf];
        s += __shfl_xor(s, 16, 64); s += __shfl_xor(s, 32, 64);
        q += __shfl_xor(q, 16, 64); q += __shfl_xor(q, 32, 64);
        if (c16 == 0) {
          atomicAdd(&bnbuf[nf * 16 + fc], s);
          atomicAdd(&bnbuf[64 + nf * 16 + fc], q);
        }
      }
      __syncthreads();
      if (t < 128) {
        int idx = (t < 64) ? (n0 + t) : (128 + n0 + (t - 64));
        atomicAdd(&ssum_out[idx], bnbuf[t]);
      }
    }
    __syncthreads();
  }
}

__device__ __forceinline__ void mg_gather(
    const u16* __restrict__ z, bool trans,
    const float* __restrict__ ssum, const float* __restrict__ gamma,
    const float* __restrict__ beta, u16* __restrict__ mean,
    const int* __restrict__ cnt, const int* __restrict__ bucket,
    float* s_sc, int t, int bid) {
  if (trans) {
    if (t < 128) {
      float m = ssum[t] * (1.0f / M_NODES);
      float var = ssum[128 + t] * (1.0f / M_NODES) - m * m;
      float s = gamma[t] * rsqrtf(var + EPS_BN);
      s_sc[t] = s;
      s_sc[128 + t] = beta[t] - m * s;
    }
    __syncthreads();
  }
  int lane = t & 63;
  int w = t >> 6;
  int slot = lane >> 4;
  int fc = lane & 15;
  float sreg[8], treg[8];
  if (trans) {
    #pragma unroll
    for (int i = 0; i < 8; ++i) { sreg[i] = s_sc[fc * 8 + i]; treg[i] = s_sc[128 + fc * 8 + i]; }
  }
  for (int node = bid * 4 + w; node < M_NODES; node += NBM * 4) {
    int deg = cnt[node];
    int nd = deg < BKT ? deg : BKT;
    const int* bk = bucket + (size_t)node * BKT;
    float a[8] = {};
    for (int j = slot; j < nd; j += 4) {
      int s = bk[j];
      uint4 v = *(const uint4*)(z + (size_t)s * 128 + fc * 8);
      float f[8] = {lo16f(v.x), hi16f(v.x), lo16f(v.y), hi16f(v.y),
                    lo16f(v.z), hi16f(v.z), lo16f(v.w), hi16f(v.w)};
      #pragma unroll
      for (int i = 0; i < 8; ++i) {
        float vv = trans ? fmaxf(fmaf(f[i], sreg[i], treg[i]), 0.f) : f[i];
        a[i] += vv;
      }
    }
    #pragma unroll
    for (int i = 0; i < 8; ++i) {
      a[i] += __shfl_xor(a[i], 16, 64);
      a[i] += __shfl_xor(a[i], 32, 64);
    }
    if (slot == 0) {
      float inv = 1.0f / (float)(deg > 1 ? deg : 1);
      uint4 r;
      r.x = (u32)f2bf(a[0] * inv) | ((u32)f2bf(a[1] * inv) << 16);
      r.y = (u32)f2bf(a[2] * inv) | ((u32)f2bf(a[3] * inv) << 16);
      r.z = (u32)f2bf(a[4] * inv) | ((u32)f2bf(a[5] * inv) << 16);
      r.w = (u32)f2bf(a[6] * inv) | ((u32)f2bf(a[7] * inv) << 16);
      *(uint4*)(mean + (size_t)node * 128 + fc * 8) = r;
    }
  }
}

__device__ __forceinline__ void mg_dec(
    const u16* __restrict__ z5, const u16* __restrict__ Bpd,
    const float* __restrict__ b1, const float* __restrict__ W2,
    float* __restrict__ out, u16* smem, int t, int bid) {
  int lane = t & 63;
  int w = t >> 6;
  int fc = lane & 15;
  int c16 = lane >> 4;
  for (int vb = bid; vb < 1564; vb += NBM) {
    int hh = vb / 782;
    int e64 = vb - hh * 782;
    int m0 = e64 * 64;
    int hb = hh * 128;

    bf16x8 af[4];
    {
      int rg = m0 + w * 16 + fc;
      rg = rg < M_NODES ? rg : M_NODES - 1;
      const u16* ar = z5 + (size_t)rg * 128 + c16 * 8;
      #pragma unroll
      for (int kt = 0; kt < 4; ++kt) af[kt] = *(const bf16x8*)(ar + kt * 32);
    }
    uint4 bst[8];
    #pragma unroll
    for (int j = 0; j < 8; ++j) {
      int s = j * 256 + t;
      int p = s >> 9;
      int sp = s & 511;
      int row = sp >> 2;
      int cc = (sp & 3) ^ ((row >> 1) & 3);
      bst[j] = *(const uint4*)(Bpd + (size_t)(hb + row) * 128 + p * 32 + cc * 8);
    }
    #pragma unroll
    for (int j = 0; j < 8; ++j) {
      int s = j * 256 + t;
      *(uint4*)&smem[s * 8] = bst[j];
    }
    __syncthreads();

    f32x4 acc[8];
    #pragma unroll
    for (int nf = 0; nf < 8; ++nf) acc[nf] = (f32x4){0.f, 0.f, 0.f, 0.f};
    #pragma unroll
    for (int kt = 0; kt < 4; ++kt) {
      #pragma unroll
      for (int nf = 0; nf < 8; ++nf) {
        int row = nf * 16 + fc;
        int cs = c16 ^ ((row >> 1) & 3);
        bf16x8 bfr = *(const bf16x8*)&smem[kt * 4096 + row * 32 + cs * 8];
        acc[nf] = __builtin_amdgcn_mfma_f32_16x16x32_bf16(af[kt], bfr, acc[nf], 0, 0, 0);
      }
    }

    float po[4][4] = {};
    #pragma unroll
    for (int nf = 0; nf < 8; ++nf) {
      int col = hb + nf * 16 + fc;
      float b1v = b1[col];
      float w2v[4];
      #pragma unroll
      for (int o = 0; o < 4; ++o) w2v[o] = W2[o * 256 + col];
      #pragma unroll
      for (int j = 0; j < 4; ++j) {
        float hv = fmaxf(acc[nf][j] + b1v, 0.f);
        #pragma unroll
        for (int o = 0; o < 4; ++o) po[j][o] = fmaf(hv, w2v[o], po[j][o]);
      }
    }
    #pragma unroll
    for (int j = 0; j < 4; ++j)
      #pragma unroll
      for (int o = 0; o < 4; ++o) {
        float v = po[j][o];
        v += __shfl_xor(v, 1, 16);
        v += __shfl_xor(v, 2, 16);
        v += __shfl_xor(v, 4, 16);
        po[j][o] = v + __shfl_xor(v, 8, 16);
      }
    if (fc == 0) {
      #pragma unroll
      for (int j = 0; j < 4; ++j) {
        int rg = m0 + w * 16 + c16 * 4 + j;
        if (rg < M_NODES) {
          #pragma unroll
          for (int o = 0; o < 4; ++o) atomicAdd(out + (size_t)rg * 4 + o, po[j][o]);
        }
      }
    }
    __syncthreads();
  }
}

__global__ __launch_bounds__(256, 2) void k_mega(MP p) {
  cg::grid_group grid = cg::this_grid();
  __shared__ __align__(16) u16 smem[16384];   // 32 KB
  __shared__ float aux[384];
  int t = threadIdx.x;
  int bid = blockIdx.x;
  int gtid = bid * 256 + t;

  // PREP
  for (int e = gtid; e < 229376; e += THM) {
    float v;
    if (e < 32768) {
      v = p.encW2[e];
    } else if (e < 196608) {
      int r = e - 32768;
      int i = r >> 15;
      int rr = r & 32767;
      int n = rr >> 8;
      int k = rr & 255;
      v = (k < 128) ? p.Wl[i * 16384 + n * 128 + k] : p.Wr[i * 16384 + n * 128 + (k - 128)];
    } else {
      v = p.decW1[e - 196608];
    }
    p.Bpack[e] = f2bf(v);
  }
  for (int i = gtid; i < M_NODES; i += THM) p.cnt[i] = 0;
  for (int i = gtid; i < 1024; i += THM) p.ssums[i] = 0.f;
  for (int i = gtid; i < M_NODES * 4; i += THM) p.out[i] = p.decb2[i & 3];
  grid.sync();

  // PLACE
  for (int e = gtid; e < E_EDGES; e += THM) {
    int d = p.dst[e];
    int q = atomicAdd(&p.cnt[d], 1);
    if (q < BKT) p.bucket[d * BKT + q] = p.src[e];
  }
  grid.sync();

  // ENCH
  {
    float* Wsf = (float*)smem;
    float* b1sf = Wsf + 2304;
    float* xsf = b1sf + 256;
    for (int i = t; i < 1792; i += 256) Wsf[(i / 7) * 9 + (i % 7)] = p.encW1[i];
    b1sf[t] = p.encb1[t];
    __syncthreads();
    int row = t >> 5;
    int cgi = t & 31;
    for (int vb = bid; vb < 6250; vb += NBM) {
      int r0 = vb * 8;
      if (t < 56) xsf[t] = p.x[(size_t)r0 * 7 + t];
      __syncthreads();
      float o[8];
      #pragma unroll
      for (int i = 0; i < 8; ++i) {
        int c = cgi * 8 + i;
        float acc = b1sf[c];
        #pragma unroll
        for (int k = 0; k < 7; ++k) acc = fmaf(xsf[row * 7 + k], Wsf[c * 9 + k], acc);
        o[i] = fmaxf(acc, 0.f);
      }
      uint4 r;
      r.x = (u32)f2bf(o[0]) | ((u32)f2bf(o[1]) << 16);
      r.y = (u32)f2bf(o[2]) | ((u32)f2bf(o[3]) << 16);
      r.z = (u32)f2bf(o[4]) | ((u32)f2bf(o[5]) << 16);
      r.w = (u32)f2bf(o[6]) | ((u32)f2bf(o[7]) << 16);
      *(uint4*)(p.h + (size_t)(r0 + row) * 256 + cgi * 8) = r;
      __syncthreads();
    }
  }
  grid.sync();

  // encoder GEMM (A=h, stride 256)
  mg_gemm(p.h, p.h + 128, 256, p.Bpack, p.encb2, p.zA, nullptr, false, false,
          nullptr, nullptr, nullptr, smem, aux, t, bid);
  grid.sync();

  // 5 conv layers
  u16* cur = p.zA;
  u16* nxt = p.zB;
  #pragma unroll 1
  for (int L = 0; L < 5; ++L) {
    const float* sin = (L == 0) ? nullptr : p.ssums + (L - 1) * 256;
    const float* gm  = (L == 0) ? nullptr : p.gamma + (size_t)(L - 1) * 128;
    const float* bt  = (L == 0) ? nullptr : p.beta + (size_t)(L - 1) * 128;
    mg_gather(cur, L > 0, sin, gm, bt, p.mean, p.cnt, p.bucket, aux, t, bid);
    grid.sync();
    mg_gemm(p.mean, cur, 128, p.Bpack + 32768 + L * 32768, p.bl + (size_t)L * 128,
            nxt, p.ssums + L * 256, L < 4, L > 0, sin, gm, bt, smem, aux, t, bid);
    grid.sync();
    u16* tmp = cur; cur = nxt; nxt = tmp;
  }

  // decoder
  mg_dec(cur, p.Bpack + 196608, p.decb1, p.decW2, p.out, smem, t, bid);
}

// ---------------- launch ----------------
extern "C" void kernel_launch(void* const* d_in, const int* in_sizes, int n_in,
                              void* d_out, int out_size, void* d_ws, size_t ws_size,
                              hipStream_t stream) {
  const float* x     = (const float*)d_in[0];
  const int*   ei    = (const int*)d_in[1];
  const float* encW1 = (const float*)d_in[2];
  const float* encb1 = (const float*)d_in[3];
  const float* encW2 = (const float*)d_in[4];
  const float* encb2 = (const float*)d_in[5];
  const float* Wl    = (const float*)d_in[6];
  const float* bl    = (const float*)d_in[7];
  const float* Wr    = (const float*)d_in[8];
  const float* gamma = (const float*)d_in[9];
  const float* beta  = (const float*)d_in[10];
  const float* decW1 = (const float*)d_in[11];
  const float* decb1 = (const float*)d_in[12];
  const float* decW2 = (const float*)d_in[13];
  const float* decb2 = (const float*)d_in[14];
  float* out = (float*)d_out;

  const int M = M_NODES, E = E_EDGES;
  char* p = (char*)d_ws;
  auto take = [&](size_t b) { char* r = p; p += (b + 255) & ~(size_t)255; return r; };
  u16* h      = (u16*)take((size_t)M * 256 * 2);
  u16* zA     = (u16*)take((size_t)M * 128 * 2);
  u16* zB     = (u16*)take((size_t)M * 128 * 2);
  u16* mean   = (u16*)take((size_t)M * 128 * 2);
  u16* Bpack  = (u16*)take((size_t)229376 * 2);
  int* cnt    = (int*)take((size_t)M * 4);
  int* bucket = (int*)take((size_t)M * BKT * 4);
  float* ssums = (float*)take((size_t)1024 * 4);

  const int* srcp = ei;
  const int* dstp = ei + E;

  // ---- attempt cooperative mega-kernel ----
  MP mp;
  mp.x = x; mp.src = srcp; mp.dst = dstp;
  mp.encW1 = encW1; mp.encb1 = encb1; mp.encb2 = encb2;
  mp.encW2 = encW2; mp.Wl = Wl; mp.bl = bl; mp.Wr = Wr;
  mp.gamma = gamma; mp.beta = beta;
  mp.decW1 = decW1; mp.decb1 = decb1; mp.decW2 = decW2; mp.decb2 = decb2;
  mp.h = h; mp.zA = zA; mp.zB = zB; mp.mean = mean; mp.Bpack = Bpack;
  mp.cnt = cnt; mp.bucket = bucket; mp.ssums = ssums; mp.out = out;
  void* args[] = { &mp };
  hipError_t err = hipLaunchCooperativeKernel((const void*)k_mega, dim3(NBM), dim3(256),
                                              args, 0, stream);
  if (err == hipSuccess) return;

  // ---- fallback: proven 13-dispatch pipeline (R17) ----
  k_prep<<<896, 256, 0, stream>>>(encW2, Wl, Wr, decW1, Bpack, cnt, ssums);
  k_place<<<(E + 255) / 256, 256, 0, stream>>>(srcp, dstp, cnt, bucket, E);
  k_enc<<<1568, 256, 0, stream>>>(x, encW1, encb1, Bpack, encb2, zA, M);

  u16* cur = zA;
  u16* nxt = zB;
  for (int i = 0; i < 5; ++i) {
    const float* sin = (i == 0) ? ssums : ssums + (i - 1) * 256;
    const float* gm  = (i == 0) ? gamma : gamma + (size_t)(i - 1) * 128;
    const float* bt  = (i == 0) ? beta  : beta + (size_t)(i - 1) * 128;
    if (i == 0) {
      k_agg<0><<<12544, 256, 0, stream>>>(cur, cnt, bucket, nullptr, nullptr, nullptr,
                                          mean, M);
      k_gemm_reg<0, 1><<<784, 256, 0, stream>>>(mean, cur, Bpack + 32768,
                                                bl, nxt, M, ssums,
                                                nullptr, nullptr, nullptr);
    } else {
      k_agg<1><<<12544, 256, 0, stream>>>(cur, cnt, bucket, sin, gm, bt, mean, M);
      if (i < 4) {
        k_gemm_reg<1, 1><<<784, 256, 0, stream>>>(mean, cur, Bpack + 32768 + i * 32768,
                                                  bl + (size_t)i * 128, nxt, M,
                                                  ssums + i * 256, sin, gm, bt);
      } else {
        k_gemm_reg<1, 0><<<784, 256, 0, stream>>>(mean, cur, Bpack + 32768 + i * 32768,
                                                  bl + (size_t)i * 128, nxt, M,
                                                  nullptr, sin, gm, bt);
      }
    }
    u16* tswap = cur; cur = nxt; nxt = tswap;
  }

  k_dec<<<784, 256, 0, stream>>>(cur, Bpack + 196608, decb1, decW2, decb2, out, M);
}

// Round 19
// 351.591 us; speedup vs baseline: 3.7510x; 3.7510x over previous
//
#include <hip/hip_runtime.h>

using u16 = unsigned short;
using u32 = unsigned int;

#define M_NODES 50000
#define E_EDGES 600000
#define EPS_BN 1e-5f
#define BKT 48

typedef __attribute__((ext_vector_type(8))) short bf16x8;
typedef __attribute__((ext_vector_type(4))) float f32x4;

__device__ __forceinline__ float bf2f(u16 v) {
  union { u32 u; float f; } x; x.u = ((u32)v) << 16; return x.f;
}
__device__ __forceinline__ float lo16f(u32 v) {
  union { u32 u; float f; } x; x.u = v << 16; return x.f;
}
__device__ __forceinline__ float hi16f(u32 v) {
  union { u32 u; float f; } x; x.u = v & 0xffff0000u; return x.f;
}
__device__ __forceinline__ u16 f2bf(float f) {
  union { float f; u32 u; } x; x.f = f;
  u32 r = x.u + 0x7fffu + ((x.u >> 16) & 1u);
  return (u16)(r >> 16);
}

// ---------------- bucket build ----------------
__global__ void k_place(const int* __restrict__ src, const int* __restrict__ dst,
                        int* __restrict__ cnt, int* __restrict__ bucket, int n) {
  int e = blockIdx.x * blockDim.x + threadIdx.x;
  if (e < n) {
    int d = dst[e];
    int p = atomicAdd(&cnt[d], 1);
    if (p < BKT) bucket[d * BKT + p] = src[e];
  }
}

// ---------------- weight prep + zero cnt/ssums ----------------
// [0,32768) encW2 [128][256]; [32768+i*32768) conv i [128][256]=[Wl|Wr]; [196608,229376) decW1 [256][128]
__global__ __launch_bounds__(256) void k_prep(const float* __restrict__ encW2,
                                              const float* __restrict__ Wl,
                                              const float* __restrict__ Wr,
                                              const float* __restrict__ decW1,
                                              u16* __restrict__ Bp,
                                              int* __restrict__ cnt0,
                                              float* __restrict__ ssums0) {
  int e = blockIdx.x * 256 + threadIdx.x;
  if (e < M_NODES) cnt0[e] = 0;
  if (e < 1024) ssums0[e] = 0.f;
  float v;
  if (e < 32768) {
    v = encW2[e];
  } else if (e < 196608) {
    int r = e - 32768;
    int i = r >> 15;
    int rr = r & 32767;
    int n = rr >> 8;
    int k = rr & 255;
    v = (k < 128) ? Wl[i * 16384 + n * 128 + k] : Wr[i * 16384 + n * 128 + (k - 128)];
  } else {
    v = decW1[e - 196608];
  }
  Bp[e] = f2bf(v);
}

// ---------------- fused mean-aggregation (+BN+relu of neighbors) ----------------
// XCD-aligned mapping: 128-node stripe ≡ blockIdx.x (mod 8). Mean only (root handled in GEMM).
template <int TRANS>
__global__ __launch_bounds__(256) void k_agg(const u16* __restrict__ z,
                                             const int* __restrict__ cnt,
                                             const int* __restrict__ bucket,
                                             const float* __restrict__ ssum,
                                             const float* __restrict__ gamma,
                                             const float* __restrict__ beta,
                                             u16* __restrict__ mean, int M) {
  __shared__ float s_sc[256];
  int t = threadIdx.x;
  if (TRANS) {
    if (t < 128) {
      float m = ssum[t] * (1.0f / M_NODES);
      float var = ssum[128 + t] * (1.0f / M_NODES) - m * m;
      float s = gamma[t] * rsqrtf(var + EPS_BN);
      s_sc[t] = s;
      s_sc[128 + t] = beta[t] - m * s;
    }
    __syncthreads();
  }
  int lane = t & 63;
  int slot = lane >> 4;
  int fc = lane & 15;
  float sreg[8], treg[8];
  if (TRANS) {
    #pragma unroll
    for (int i = 0; i < 8; ++i) { sreg[i] = s_sc[fc * 8 + i]; treg[i] = s_sc[128 + fc * 8 + i]; }
  }
  int rx = blockIdx.x & 7;
  int kx = blockIdx.x >> 3;
  int strip = rx + 8 * (kx >> 5);
  int nb = strip * 32 + (kx & 31);
  int node = nb * 4 + (t >> 6);
  if (node >= M) return;

  int deg = cnt[node];
  int nd = deg < BKT ? deg : BKT;
  const int* bk = bucket + (size_t)node * BKT;
  float a[8] = {};
  for (int j = slot; j < nd; j += 4) {
    int s = bk[j];
    uint4 v = *(const uint4*)(z + (size_t)s * 128 + fc * 8);
    float f[8] = {lo16f(v.x), hi16f(v.x), lo16f(v.y), hi16f(v.y),
                  lo16f(v.z), hi16f(v.z), lo16f(v.w), hi16f(v.w)};
    #pragma unroll
    for (int i = 0; i < 8; ++i) {
      float vv = TRANS ? fmaxf(fmaf(f[i], sreg[i], treg[i]), 0.f) : f[i];
      a[i] += vv;
    }
  }
  #pragma unroll
  for (int i = 0; i < 8; ++i) {
    a[i] += __shfl_xor(a[i], 16, 64);
    a[i] += __shfl_xor(a[i], 32, 64);
  }
  if (slot == 0) {
    float inv = 1.0f / (float)(deg > 1 ? deg : 1);
    uint4 r;
    r.x = (u32)f2bf(a[0] * inv) | ((u32)f2bf(a[1] * inv) << 16);
    r.y = (u32)f2bf(a[2] * inv) | ((u32)f2bf(a[3] * inv) << 16);
    r.z = (u32)f2bf(a[4] * inv) | ((u32)f2bf(a[5] * inv) << 16);
    r.w = (u32)f2bf(a[6] * inv) | ((u32)f2bf(a[7] * inv) << 16);
    *(uint4*)(mean + (size_t)node * 128 + fc * 8) = r;
  }
}

// ================= conv GEMM: A in regs, A2=raw z with in-register BN+relu =================
// XCD-aligned: stripe s ≡ blockIdx.x (mod 8). launch 784 blocks. BM=128, BN=64 (2 col-halves).
template <int TRANS, int DO_STATS>
__global__ __launch_bounds__(256) void k_gemm_reg(
    const u16* __restrict__ A1, const u16* __restrict__ A2,
    const u16* __restrict__ Bp, const float* __restrict__ bias,
    u16* __restrict__ C, int M, float* __restrict__ ssum_out,
    const float* __restrict__ ssum_in, const float* __restrict__ gamma,
    const float* __restrict__ beta) {
  __shared__ __align__(16) u16 Bs[8][2048];   // 32KB; reused as C-stage [128][64]
  __shared__ float bnbuf[128];
  __shared__ float s_scS[256];
  int t = threadIdx.x;
  int lane = t & 63;
  int w = t >> 6;
  int rx = blockIdx.x & 7;
  int hx = (blockIdx.x >> 3) & 1;
  int qx = blockIdx.x >> 4;               // [0,49)
  int s128 = qx * 8 + rx;
  int m0 = s128 * 128;
  if (m0 >= M) return;
  int n0 = hx * 64;
  int fc = lane & 15;
  int c16 = lane >> 4;

  if (DO_STATS && t < 128) bnbuf[t] = 0.f;

  // ---- B: plain uint4 loads to regs ----
  uint4 bst[8];
  #pragma unroll
  for (int j = 0; j < 8; ++j) {
    int s = j * 256 + t;
    int p = s >> 8;
    int sp = s & 255;
    int row = sp >> 2;
    int cc = (sp & 3) ^ ((row >> 1) & 3);
    bst[j] = *(const uint4*)(Bp + (size_t)(n0 + row) * 256 + p * 32 + cc * 8);
  }

  // ---- A fragments straight to registers ----
  bf16x8 af[8][2];
  int wrb = m0 + w * 32;
  #pragma unroll
  for (int mf = 0; mf < 2; ++mf) {
    int rg = wrb + mf * 16 + fc;
    rg = rg < M ? rg : M - 1;
    const u16* a1r = A1 + (size_t)rg * 128 + c16 * 8;
    const u16* a2r = A2 + (size_t)rg * 128 + c16 * 8;
    #pragma unroll
    for (int kt = 0; kt < 4; ++kt) af[kt][mf] = *(const bf16x8*)(a1r + kt * 32);
    #pragma unroll
    for (int kt = 0; kt < 4; ++kt) af[4 + kt][mf] = *(const bf16x8*)(a2r + kt * 32);
  }

  // ---- BN scale/shift table (overlaps with in-flight loads) ----
  if (TRANS && t < 128) {
    float m = ssum_in[t] * (1.0f / M_NODES);
    float var = ssum_in[128 + t] * (1.0f / M_NODES) - m * m;
    float s = gamma[t] * rsqrtf(var + EPS_BN);
    s_scS[t] = s;
    s_scS[128 + t] = beta[t] - m * s;
  }

  // ---- write B to LDS ----
  #pragma unroll
  for (int j = 0; j < 8; ++j) {
    int s = j * 256 + t;
    *(uint4*)&((u16*)Bs)[s * 8] = bst[j];
  }
  __syncthreads();

  // ---- apply BN+relu to A2 fragments in-register ----
  if (TRANS) {
    #pragma unroll
    for (int kt = 0; kt < 4; ++kt) {
      #pragma unroll
      for (int mf = 0; mf < 2; ++mf) {
        bf16x8 v = af[4 + kt][mf];
        bf16x8 o;
        #pragma unroll
        for (int i = 0; i < 8; ++i) {
          int feat = kt * 32 + c16 * 8 + i;
          float fv = bf2f((u16)v[i]);
          o[i] = (short)f2bf(fmaxf(fmaf(fv, s_scS[feat], s_scS[128 + feat]), 0.f));
        }
        af[4 + kt][mf] = o;
      }
    }
  }

  // ---- barrier-free K-loop ----
  f32x4 acc[2][4] = {};
  #pragma unroll
  for (int kt = 0; kt < 8; ++kt) {
    bf16x8 bfr[4];
    #pragma unroll
    for (int nf = 0; nf < 4; ++nf) {
      int row = nf * 16 + fc;
      int cs = c16 ^ ((row >> 1) & 3);
      bfr[nf] = *(const bf16x8*)&Bs[kt][row * 32 + cs * 8];
    }
    #pragma unroll
    for (int mf = 0; mf < 2; ++mf)
      #pragma unroll
      for (int nf = 0; nf < 4; ++nf)
        acc[mf][nf] = __builtin_amdgcn_mfma_f32_16x16x32_bf16(af[kt][mf], bfr[nf], acc[mf][nf], 0, 0, 0);
  }

  // ---- epilogue ----
  float breg[4];
  #pragma unroll
  for (int nf = 0; nf < 4; ++nf) breg[nf] = bias[n0 + nf * 16 + fc];

  __syncthreads();
  u16* Cl = (u16*)Bs;
  float cs_[4] = {}, cq_[4] = {};
  #pragma unroll
  for (int mf = 0; mf < 2; ++mf) {
    #pragma unroll
    for (int j = 0; j < 4; ++j) {
      int rl = w * 32 + mf * 16 + c16 * 4 + j;
      bool valid = (m0 + rl) < M;
      #pragma unroll
      for (int nf = 0; nf < 4; ++nf) {
        float v = acc[mf][nf][j] + breg[nf];
        Cl[rl * 64 + nf * 16 + fc] = f2bf(v);
        if (DO_STATS && valid) { cs_[nf] += v; cq_[nf] = fmaf(v, v, cq_[nf]); }
      }
    }
  }
  __syncthreads();
  #pragma unroll
  for (int j2 = 0; j2 < 4; ++j2) {
    int ci = j2 * 256 + t;
    int row = ci >> 3;
    int cx = ci & 7;
    int rg = m0 + row;
    if (rg < M)
      *(uint4*)(C + (size_t)rg * 128 + n0 + cx * 8) = *(const uint4*)&Cl[row * 64 + cx * 8];
  }

  if (DO_STATS) {
    #pragma unroll
    for (int nf = 0; nf < 4; ++nf) {
      float s = cs_[nf], q = cq_[nf];
      s += __shfl_xor(s, 16, 64); s += __shfl_xor(s, 32, 64);
      q += __shfl_xor(q, 16, 64); q += __shfl_xor(q, 32, 64);
      if (c16 == 0) {
        atomicAdd(&bnbuf[nf * 16 + fc], s);
        atomicAdd(&bnbuf[64 + nf * 16 + fc], q);
      }
    }
    __syncthreads();
    if (t < 128) {
      int idx = (t < 64) ? (n0 + t) : (128 + n0 + (t - 64));
      atomicAdd(&ssum_out[idx], bnbuf[t]);
    }
  }
}

// ================= fused encoder: x-MLP -> LDS A-tile -> GEMM. BM=64, 1D grid 1568 =================
// XCD-aligned: 128-row super-stripe s ≡ blockIdx.x (mod 8).
__global__ __launch_bounds__(256) void k_enc(
    const float* __restrict__ x, const float* __restrict__ W1,
    const float* __restrict__ b1, const u16* __restrict__ Bp,
    const float* __restrict__ bias, u16* __restrict__ C, int M) {
  __shared__ __align__(16) u16 As[8][2048];   // 32KB; reused as C-stage [64][64]
  __shared__ __align__(16) u16 Bs[8][2048];   // 32KB
  __shared__ float xs[448];
  int t = threadIdx.x;
  int lane = t & 63;
  int w = t >> 6;
  int rx = blockIdx.x & 7;
  int kx = (blockIdx.x >> 3) & 3;
  int qx = blockIdx.x >> 5;               // [0,49)
  int s128 = qx * 8 + rx;
  int e64 = s128 * 2 + (kx & 1);          // 64-row stripe
  int m0 = e64 * 64;
  if (m0 >= M) return;
  int n0c = (kx >> 1) * 64;
  int fc = lane & 15;
  int c16 = lane >> 4;

  uint4 bst[8];
  #pragma unroll
  for (int j = 0; j < 8; ++j) {
    int s = j * 256 + t;
    int p = s >> 8;
    int sp = s & 255;
    int row = sp >> 2;
    int cc = (sp & 3) ^ ((row >> 1) & 3);
    bst[j] = *(const uint4*)(Bp + (size_t)(n0c + row) * 256 + p * 32 + cc * 8);
  }
  for (int i = t; i < 448; i += 256) {
    int gi = m0 * 7 + i;
    xs[i] = (gi < M * 7) ? x[gi] : 0.f;
  }
  float w1r[7];
  #pragma unroll
  for (int k = 0; k < 7; ++k) w1r[k] = W1[t * 7 + k];
  float b1r = b1[t];
  __syncthreads();

  int p = t >> 5;
  int cq = (t & 31) >> 3;
  int e8 = t & 7;
  for (int r = 0; r < 64; ++r) {
    float acc = b1r;
    #pragma unroll
    for (int k = 0; k < 7; ++k) acc = fmaf(w1r[k], xs[r * 7 + k], acc);
    As[p][r * 32 + (cq ^ ((r >> 1) & 3)) * 8 + e8] = f2bf(fmaxf(acc, 0.f));
  }
  #pragma unroll
  for (int j = 0; j < 8; ++j) {
    int s = j * 256 + t;
    *(uint4*)&((u16*)Bs)[s * 8] = bst[j];
  }
  __syncthreads();

  f32x4 acc[2][2] = {};
  #pragma unroll
  for (int kt = 0; kt < 8; ++kt) {
    bf16x8 afr[2], bfr[2];
    #pragma unroll
    for (int mf = 0; mf < 2; ++mf) {
      int row = (w & 1) * 32 + mf * 16 + fc;
      int cs = c16 ^ ((row >> 1) & 3);
      afr[mf] = *(const bf16x8*)&As[kt][row * 32 + cs * 8];
    }
    #pragma unroll
    for (int nf = 0; nf < 2; ++nf) {
      int row = (w >> 1) * 32 + nf * 16 + fc;
      int cs = c16 ^ ((row >> 1) & 3);
      bfr[nf] = *(const bf16x8*)&Bs[kt][row * 32 + cs * 8];
    }
    #pragma unroll
    for (int mf = 0; mf < 2; ++mf)
      #pragma unroll
      for (int nf = 0; nf < 2; ++nf)
        acc[mf][nf] = __builtin_amdgcn_mfma_f32_16x16x32_bf16(afr[mf], bfr[nf], acc[mf][nf], 0, 0, 0);
  }

  float breg[2];
  #pragma unroll
  for (int nf = 0; nf < 2; ++nf) breg[nf] = bias[n0c + (w >> 1) * 32 + nf * 16 + fc];
  __syncthreads();
  u16* Cl = (u16*)As;
  #pragma unroll
  for (int mf = 0; mf < 2; ++mf)
    #pragma unroll
    for (int j = 0; j < 4; ++j) {
      int rl = (w & 1) * 32 + mf * 16 + c16 * 4 + j;
      #pragma unroll
      for (int nf = 0; nf < 2; ++nf)
        Cl[rl * 64 + (w >> 1) * 32 + nf * 16 + fc] = f2bf(acc[mf][nf][j] + breg[nf]);
    }
  __syncthreads();
  #pragma unroll
  for (int j2 = 0; j2 < 2; ++j2) {
    int ci = j2 * 256 + t;
    int row = ci >> 3;
    int cx = ci & 7;
    int rg = m0 + row;
    if (rg < M)
      *(uint4*)(C + (size_t)rg * 128 + n0c + cx * 8) = *(const uint4*)&Cl[row * 64 + cx * 8];
  }
}

// ================= decoder: BM=64, full N=256 per block, 1D grid 784 =================
__global__ __launch_bounds__(256) void k_dec(
    const u16* __restrict__ z5, const u16* __restrict__ Bpd,
    const float* __restrict__ b1, const float* __restrict__ W2,
    const float* __restrict__ b2, float* __restrict__ out, int M) {
  __shared__ __align__(16) u16 Bs[4][8192];
  int t = threadIdx.x;
  int lane = t & 63;
  int w = t >> 6;
  int rx = blockIdx.x & 7;
  int kx = (blockIdx.x >> 3) & 1;
  int qx = blockIdx.x >> 4;
  int s128 = qx * 8 + rx;
  int e64 = s128 * 2 + kx;
  int m0 = e64 * 64;
  if (m0 >= M) return;
  int fc = lane & 15;
  int c16 = lane >> 4;

  bf16x8 af[4];
  {
    int rg = m0 + w * 16 + fc;
    rg = rg < M ? rg : M - 1;
    const u16* ar = z5 + (size_t)rg * 128 + c16 * 8;
    #pragma unroll
    for (int kt = 0; kt < 4; ++kt) af[kt] = *(const bf16x8*)(ar + kt * 32);
  }

  #pragma unroll
  for (int r = 0; r < 2; ++r) {
    uint4 bst[8];
    #pragma unroll
    for (int j = 0; j < 8; ++j) {
      int s = r * 2048 + j * 256 + t;
      int p = s >> 10;
      int sp = s & 1023;
      int row = sp >> 2;
      int cc = (sp & 3) ^ ((row >> 1) & 3);
      bst[j] = *(const uint4*)(Bpd + (size_t)row * 128 + p * 32 + cc * 8);
    }
    #pragma unroll
    for (int j = 0; j < 8; ++j) {
      int s = r * 2048 + j * 256 + t;
      *(uint4*)&((u16*)Bs)[s * 8] = bst[j];
    }
  }
  __syncthreads();

  f32x4 acc[16];
  #pragma unroll
  for (int nf = 0; nf < 16; ++nf) acc[nf] = (f32x4){0.f, 0.f, 0.f, 0.f};
  #pragma unroll
  for (int kt = 0; kt < 4; ++kt) {
    #pragma unroll
    for (int nf = 0; nf < 16; ++nf) {
      int row = nf * 16 + fc;
      int cs = c16 ^ ((row >> 1) & 3);
      bf16x8 bfr = *(const bf16x8*)&Bs[kt][row * 32 + cs * 8];
      acc[nf] = __builtin_amdgcn_mfma_f32_16x16x32_bf16(af[kt], bfr, acc[nf], 0, 0, 0);
    }
  }

  float po[4][4] = {};
  #pragma unroll
  for (int nf = 0; nf < 16; ++nf) {
    int col = nf * 16 + fc;
    float b1v = b1[col];
    float w2v[4];
    #pragma unroll
    for (int o = 0; o < 4; ++o) w2v[o] = W2[o * 256 + col];
    #pragma unroll
    for (int j = 0; j < 4; ++j) {
      float hv = fmaxf(acc[nf][j] + b1v, 0.f);
      #pragma unroll
      for (int o = 0; o < 4; ++o) po[j][o] = fmaf(hv, w2v[o], po[j][o]);
    }
  }
  #pragma unroll
  for (int j = 0; j < 4; ++j)
    #pragma unroll
    for (int o = 0; o < 4; ++o) {
      float v = po[j][o];
      v += __shfl_xor(v, 1, 16);
      v += __shfl_xor(v, 2, 16);
      v += __shfl_xor(v, 4, 16);
      po[j][o] = v + __shfl_xor(v, 8, 16);
    }
  if (fc == 0) {
    #pragma unroll
    for (int j = 0; j < 4; ++j) {
      int rg = m0 + w * 16 + c16 * 4 + j;
      if (rg < M) {
        #pragma unroll
        for (int o = 0; o < 4; ++o) out[(size_t)rg * 4 + o] = po[j][o] + b2[o];
      }
    }
  }
}

// ---------------- launch ----------------
extern "C" void kernel_launch(void* const* d_in, const int* in_sizes, int n_in,
                              void* d_out, int out_size, void* d_ws, size_t ws_size,
                              hipStream_t stream) {
  const float* x     = (const float*)d_in[0];
  const int*   ei    = (const int*)d_in[1];
  const float* encW1 = (const float*)d_in[2];
  const float* encb1 = (const float*)d_in[3];
  const float* encW2 = (const float*)d_in[4];
  const float* encb2 = (const float*)d_in[5];
  const float* Wl    = (const float*)d_in[6];
  const float* bl    = (const float*)d_in[7];
  const float* Wr    = (const float*)d_in[8];
  const float* gamma = (const float*)d_in[9];
  const float* beta  = (const float*)d_in[10];
  const float* decW1 = (const float*)d_in[11];
  const float* decb1 = (const float*)d_in[12];
  const float* decW2 = (const float*)d_in[13];
  const float* decb2 = (const float*)d_in[14];
  float* out = (float*)d_out;

  const int M = M_NODES, E = E_EDGES;
  char* p = (char*)d_ws;
  auto take = [&](size_t b) { char* r = p; p += (b + 255) & ~(size_t)255; return r; };
  u16* zA     = (u16*)take((size_t)M * 128 * 2);
  u16* zB     = (u16*)take((size_t)M * 128 * 2);
  u16* mean   = (u16*)take((size_t)M * 128 * 2);
  u16* Bpack  = (u16*)take((size_t)229376 * 2);
  int* cnt    = (int*)take((size_t)M * 4);
  int* bucket = (int*)take((size_t)M * BKT * 4);
  float* ssums = (float*)take((size_t)1024 * 4);

  const int* srcp = ei;
  const int* dstp = ei + E;

  k_prep<<<896, 256, 0, stream>>>(encW2, Wl, Wr, decW1, Bpack, cnt, ssums);
  k_place<<<(E + 255) / 256, 256, 0, stream>>>(srcp, dstp, cnt, bucket, E);
  k_enc<<<1568, 256, 0, stream>>>(x, encW1, encb1, Bpack, encb2, zA, M);

  u16* cur = zA;
  u16* nxt = zB;
  for (int i = 0; i < 5; ++i) {
    const float* sin = (i == 0) ? ssums : ssums + (i - 1) * 256;
    const float* gm  = (i == 0) ? gamma : gamma + (size_t)(i - 1) * 128;
    const float* bt  = (i == 0) ? beta  : beta + (size_t)(i - 1) * 128;
    if (i == 0) {
      k_agg<0><<<12544, 256, 0, stream>>>(cur, cnt, bucket, nullptr, nullptr, nullptr,
                                          mean, M);
      k_gemm_reg<0, 1><<<784, 256, 0, stream>>>(mean, cur, Bpack + 32768,
                                                bl, nxt, M, ssums,
                                                nullptr, nullptr, nullptr);
    } else {
      k_agg<1><<<12544, 256, 0, stream>>>(cur, cnt, bucket, sin, gm, bt, mean, M);
      if (i < 4) {
        k_gemm_reg<1, 1><<<784, 256, 0, stream>>>(mean, cur, Bpack + 32768 + i * 32768,
                                                  bl + (size_t)i * 128, nxt, M,
                                                  ssums + i * 256, sin, gm, bt);
      } else {
        k_gemm_reg<1, 0><<<784, 256, 0, stream>>>(mean, cur, Bpack + 32768 + i * 32768,
                                                  bl + (size_t)i * 128, nxt, M,
                                                  nullptr, sin, gm, bt);
      }
    }
    u16* tswap = cur; cur = nxt; nxt = tswap;
  }

  k_dec<<<784, 256, 0, stream>>>(cur, Bpack + 196608, decb1, decW2, decb2, out, M);
}